// Round 2
// baseline (172.414 us; speedup 1.0000x reference)
//
#include <hip/hip_runtime.h>

// Row-wise cosine hinge loss.
//   j = (i + 1 + neg_idx[i]) % B
//   hinge_i = relu(1 - cos(t_i, o_i) + cos(t_j, o_i))
//   out = sum_i hinge_i / B
//
// TLP-max structure: ONE row per wave, 4096 blocks (B/4), VGPR capped at 64
// via __launch_bounds__(256, 8) so 8 waves/EU (32/CU) are resident with
// continuous block turnover. Round-1 counters showed the 1024-block
// persistent-wave version ran at only 2.4 TB/s (30% HBM) with 16 waves/CU
// and no turnover -> latency-bound, not BW-bound. This matches the shape of
// the 6.29 TB/s streaming probe (many short low-VGPR waves).

#define EPS 1e-6f

typedef float f4 __attribute__((ext_vector_type(4)));

// VALU-pipe wave reduction via DPP; lane 63 holds the 64-lane sum.
#define DPP_STEP(x, ctrl, rm, bm)                                             \
    x += __int_as_float(__builtin_amdgcn_update_dpp(                          \
        0, __float_as_int(x), (ctrl), (rm), (bm), true))

__device__ __forceinline__ float dpp_wave_sum(float x) {
    DPP_STEP(x, 0x111, 0xf, 0xf);  // row_shr:1
    DPP_STEP(x, 0x112, 0xf, 0xf);  // row_shr:2
    DPP_STEP(x, 0x114, 0xf, 0xe);  // row_shr:4
    DPP_STEP(x, 0x118, 0xf, 0xc);  // row_shr:8
    DPP_STEP(x, 0x142, 0xa, 0xf);  // row_bcast:15
    DPP_STEP(x, 0x143, 0xc, 0xf);  // row_bcast:31
    return x;                      // valid in lane 63
}

__global__ __launch_bounds__(256, 8) void hinge_cos_kernel(
    const float* __restrict__ outm,   // [B, D]
    const float* __restrict__ tgt,    // [B, D]
    const int*   __restrict__ negidx, // [B]
    float* __restrict__ res,          // [1] scalar (pre-zeroed)
    int B, int D, float invB) {

    const int lane = threadIdx.x & 63;
    const int wave = threadIdx.x >> 6;
    const int i    = blockIdx.x * 4 + wave;   // one row per wave

    float h = 0.f;
    if (i < B) {
        // Wave-uniform index load (compiles to s_load); issued first so the
        // gather addresses resolve while o/t loads are in flight.
        const int g = negidx[i];

        const f4* o4 = (const f4*)(outm + (size_t)i * D);
        const f4* t4 = (const f4*)(tgt  + (size_t)i * D);

        f4 o[4], t[4], n[4];
#pragma unroll
        for (int k = 0; k < 4; ++k) o[k] = o4[lane + 64 * k];
#pragma unroll
        for (int k = 0; k < 4; ++k) t[k] = t4[lane + 64 * k];

        int j = i + 1 + g; if (j >= B) j -= B;
        const f4* n4 = (const f4*)(tgt + (size_t)j * D);
#pragma unroll
        for (int k = 0; k < 4; ++k) n[k] = n4[lane + 64 * k];

        float dto = 0.f, dno = 0.f, oo = 0.f, tt = 0.f, nn = 0.f;
#pragma unroll
        for (int k = 0; k < 4; ++k) {
            dto += o[k].x*t[k].x + o[k].y*t[k].y + o[k].z*t[k].z + o[k].w*t[k].w;
            dno += o[k].x*n[k].x + o[k].y*n[k].y + o[k].z*n[k].z + o[k].w*n[k].w;
            oo  += o[k].x*o[k].x + o[k].y*o[k].y + o[k].z*o[k].z + o[k].w*o[k].w;
            tt  += t[k].x*t[k].x + t[k].y*t[k].y + t[k].z*t[k].z + t[k].w*t[k].w;
            nn  += n[k].x*n[k].x + n[k].y*n[k].y + n[k].z*n[k].z + n[k].w*n[k].w;
        }
        dto = dpp_wave_sum(dto);
        dno = dpp_wave_sum(dno);
        oo  = dpp_wave_sum(oo);
        tt  = dpp_wave_sum(tt);
        nn  = dpp_wave_sum(nn);
        float no = sqrtf(oo);
        float hv = 1.f - dto / fmaxf(sqrtf(tt) * no, EPS)
                       + dno / fmaxf(sqrtf(nn) * no, EPS);
        h = fmaxf(hv, 0.f);       // valid in lane 63
    }

    // Block-level: lane 63 of each wave holds its row's hinge; one atomic
    // per block (4096 atomics total, spread over the kernel's lifetime).
    __shared__ float red[4];
    if (lane == 63) red[wave] = h;
    __syncthreads();
    if (threadIdx.x == 0) {
        float s = red[0] + red[1] + red[2] + red[3];
        atomicAdd(res, s * invB);
    }
}

extern "C" void kernel_launch(void* const* d_in, const int* in_sizes, int n_in,
                              void* d_out, int out_size, void* d_ws, size_t ws_size,
                              hipStream_t stream) {
    const float* outm   = (const float*)d_in[0];
    const float* tgt    = (const float*)d_in[1];
    const int*   negidx = (const int*)d_in[2];
    float* res = (float*)d_out;

    const int B = in_sizes[2];
    const int D = in_sizes[0] / B;

    (void)hipMemsetAsync(res, 0, sizeof(float), stream);

    // One row per wave: 4 rows per 256-thread block.
    const int blocks = (B + 3) / 4;
    hinge_cos_kernel<<<blocks, 256, 0, stream>>>(outm, tgt, negidx, res, B, D,
                                                 1.0f / (float)B);
}

// Round 3
// 151.592 us; speedup vs baseline: 1.1374x; 1.1374x over previous
//
#include <hip/hip_runtime.h>

// Row-wise cosine hinge loss.
//   j = (i + 1 + neg_idx[i]) % B
//   hinge_i = relu(1 - cos(t_i, o_i) + cos(t_j, o_i))
//   out = sum_i hinge_i / B
//
// R3: same per-wave pipeline as the 40.7us R1 version (depth-2 A/B register
// buffers, launch_bounds(256,4) so the compiler emits the 64-VGPR
// ~12-outstanding-loads schedule), but 2 rows/wave instead of 4 ->
// 2048 blocks = 8 blocks/CU = 32 waves/CU. R1 was grid-limited (16 waves/CU
// resident while VGPR=64 allows 32). R2 proved occupancy alone is useless if
// the register budget forces a load convoy (VGPR=32 -> 1.48 TB/s); this
// version doubles waves while preserving per-wave outstanding loads.

#define EPS 1e-6f

typedef float f4 __attribute__((ext_vector_type(4)));

// VALU-pipe wave reduction via DPP; lane 63 holds the 64-lane sum.
#define DPP_STEP(x, ctrl, rm, bm)                                             \
    x += __int_as_float(__builtin_amdgcn_update_dpp(                          \
        0, __float_as_int(x), (ctrl), (rm), (bm), true))

__device__ __forceinline__ float dpp_wave_sum(float x) {
    DPP_STEP(x, 0x111, 0xf, 0xf);  // row_shr:1
    DPP_STEP(x, 0x112, 0xf, 0xf);  // row_shr:2
    DPP_STEP(x, 0x114, 0xf, 0xe);  // row_shr:4
    DPP_STEP(x, 0x118, 0xf, 0xc);  // row_shr:8
    DPP_STEP(x, 0x142, 0xa, 0xf);  // row_bcast:15
    DPP_STEP(x, 0x143, 0xc, 0xf);  // row_bcast:31
    return x;                      // valid in lane 63
}

struct RowBuf {
    f4 o[4], t[4], n[4];
};

__device__ __forceinline__ void issue_loads(RowBuf& rb,
                                            const float* __restrict__ outm,
                                            const float* __restrict__ tgt,
                                            int i, int j, int lane, int D) {
    const f4* o4 = (const f4*)(outm + (size_t)i * D);
    const f4* t4 = (const f4*)(tgt  + (size_t)i * D);
    const f4* n4 = (const f4*)(tgt  + (size_t)j * D);
#pragma unroll
    for (int k = 0; k < 4; ++k)
        rb.o[k] = __builtin_nontemporal_load(&o4[lane + 64 * k]);  // single-use stream
#pragma unroll
    for (int k = 0; k < 4; ++k) rb.t[k] = t4[lane + 64 * k];
#pragma unroll
    for (int k = 0; k < 4; ++k) rb.n[k] = n4[lane + 64 * k];
}

// Returns this row's hinge value (valid in lane 63; other lanes garbage).
__device__ __forceinline__ float consume(const RowBuf& rb) {
    float dto = 0.f, dno = 0.f, oo = 0.f, tt = 0.f, nn = 0.f;
#pragma unroll
    for (int k = 0; k < 4; ++k) {
        dto += rb.o[k].x*rb.t[k].x + rb.o[k].y*rb.t[k].y + rb.o[k].z*rb.t[k].z + rb.o[k].w*rb.t[k].w;
        dno += rb.o[k].x*rb.n[k].x + rb.o[k].y*rb.n[k].y + rb.o[k].z*rb.n[k].z + rb.o[k].w*rb.n[k].w;
        oo  += rb.o[k].x*rb.o[k].x + rb.o[k].y*rb.o[k].y + rb.o[k].z*rb.o[k].z + rb.o[k].w*rb.o[k].w;
        tt  += rb.t[k].x*rb.t[k].x + rb.t[k].y*rb.t[k].y + rb.t[k].z*rb.t[k].z + rb.t[k].w*rb.t[k].w;
        nn  += rb.n[k].x*rb.n[k].x + rb.n[k].y*rb.n[k].y + rb.n[k].z*rb.n[k].z + rb.n[k].w*rb.n[k].w;
    }
    dto = dpp_wave_sum(dto);
    dno = dpp_wave_sum(dno);
    oo  = dpp_wave_sum(oo);
    tt  = dpp_wave_sum(tt);
    nn  = dpp_wave_sum(nn);
    float no = sqrtf(oo);
    float h  = 1.f - dto / fmaxf(sqrtf(tt) * no, EPS)
                   + dno / fmaxf(sqrtf(nn) * no, EPS);
    return fmaxf(h, 0.f);
}

__global__ __launch_bounds__(256, 4) void hinge_cos_kernel(
    const float* __restrict__ outm,   // [B, D]
    const float* __restrict__ tgt,    // [B, D]
    const int*   __restrict__ negidx, // [B]
    float* __restrict__ res,          // [1] scalar (pre-zeroed)
    int B, int D, float invB) {

    const int lane  = threadIdx.x & 63;
    const int wave  = threadIdx.x >> 6;
    const int wpb   = blockDim.x >> 6;           // 4
    const int gwave = blockIdx.x * wpb + wave;
    const int nwav  = gridDim.x * wpb;           // 8192

    // Static 2-row assignment: rows gwave and gwave + nwav.
    const int i0 = gwave;
    const int i1 = i0 + nwav;
    const bool v0 = i0 < B, v1 = i1 < B;

    // Hoist both gather indices: independent loads, no dependent load on the
    // per-row issue path.
    int g0 = v0 ? negidx[i0] : 0;
    int g1 = v1 ? negidx[i1] : 0;
    int j0 = i0 + 1 + g0; if (j0 >= B) j0 -= B;
    int j1 = i1 + 1 + g1; if (j1 >= B) j1 -= B;

    float acc = 0.f;                              // per-wave hinge sum (lane 63)
    RowBuf bufA, bufB;                            // named: never runtime-indexed

    if (v0) issue_loads(bufA, outm, tgt, i0, j0, lane, D);
    if (v1) issue_loads(bufB, outm, tgt, i1, j1, lane, D);
    if (v0) { float h = consume(bufA); if (lane == 63) acc += h; }
    if (v1) { float h = consume(bufB); if (lane == 63) acc += h; }

    // Block-level: lane 63 of each wave holds its partial; one atomic per block.
    __shared__ float red[4];
    if (lane == 63) red[wave] = acc;
    __syncthreads();
    if (threadIdx.x == 0) {
        float s = red[0] + red[1] + red[2] + red[3];
        atomicAdd(res, s * invB);
    }
}

extern "C" void kernel_launch(void* const* d_in, const int* in_sizes, int n_in,
                              void* d_out, int out_size, void* d_ws, size_t ws_size,
                              hipStream_t stream) {
    const float* outm   = (const float*)d_in[0];
    const float* tgt    = (const float*)d_in[1];
    const int*   negidx = (const int*)d_in[2];
    float* res = (float*)d_out;

    const int B = in_sizes[2];
    const int D = in_sizes[0] / B;

    (void)hipMemsetAsync(res, 0, sizeof(float), stream);

    // Two rows per wave: nwav = ceil(B/2), 4 waves per 256-thread block.
    const int nwav   = (B + 1) / 2;               // 8192
    const int blocks = (nwav + 3) / 4;            // 2048
    hinge_cos_kernel<<<blocks, 256, 0, stream>>>(outm, tgt, negidx, res, B, D,
                                                 1.0f / (float)B);
}

// Round 4
// 149.341 us; speedup vs baseline: 1.1545x; 1.0151x over previous
//
#include <hip/hip_runtime.h>

// Row-wise cosine hinge loss.
//   j = (i + 1 + neg_idx[i]) % B
//   hinge_i = relu(1 - cos(t_i, o_i) + cos(t_j, o_i))
//   out = sum_i hinge_i / B
//
// R4: ISA-level software pipeline. R1/R3 counters proved the compiler
// collapses any HIP-level register double-buffer (VGPR=52/64, should be
// ~120): loads get re-ordered into a convoy and per-wave outstanding bytes
// cap BW at ~2.3 TB/s while the same chip fills at 6.5 TB/s. Fix per guide
// rule 18 / T4: issue 24 global_load_dwordx4 (2 rows x 12) as inline asm
// into named f4 outputs the allocator cannot recycle, then counted waits:
//   s_waitcnt vmcnt(12) -> consume row A (row B's 12KB still in flight)
//   s_waitcnt vmcnt(0)  -> consume row B
// sched_barrier(0) after each wait stops the MI scheduler hoisting the
// register-only consumers past the wait ("memory" does not order them).

#define EPS 1e-6f

typedef float f4 __attribute__((ext_vector_type(4)));

// VALU-pipe wave reduction via DPP; lane 63 holds the 64-lane sum.
#define DPP_STEP(x, ctrl, rm, bm)                                             \
    x += __int_as_float(__builtin_amdgcn_update_dpp(                          \
        0, __float_as_int(x), (ctrl), (rm), (bm), true))

__device__ __forceinline__ float dpp_wave_sum(float x) {
    DPP_STEP(x, 0x111, 0xf, 0xf);  // row_shr:1
    DPP_STEP(x, 0x112, 0xf, 0xf);  // row_shr:2
    DPP_STEP(x, 0x114, 0xf, 0xe);  // row_shr:4
    DPP_STEP(x, 0x118, 0xf, 0xc);  // row_shr:8
    DPP_STEP(x, 0x142, 0xa, 0xf);  // row_bcast:15
    DPP_STEP(x, 0x143, 0xc, 0xf);  // row_bcast:31
    return x;                      // valid in lane 63
}

// 4x global_load_dwordx4 covering one 4KB row-slice (lane base + k*1024B).
// Early-clobber outputs: results land asynchronously, must not alias addr.
#define LOAD4(d0, d1, d2, d3, p)                                              \
    asm volatile("global_load_dwordx4 %0, %4, off\n\t"                        \
                 "global_load_dwordx4 %1, %4, off offset:1024\n\t"            \
                 "global_load_dwordx4 %2, %4, off offset:2048\n\t"            \
                 "global_load_dwordx4 %3, %4, off offset:3072"                \
                 : "=&v"(d0), "=&v"(d1), "=&v"(d2), "=&v"(d3)                 \
                 : "v"(p))

// Same, non-temporal (single-use o stream: keep it out of L2).
#define LOAD4_NT(d0, d1, d2, d3, p)                                           \
    asm volatile("global_load_dwordx4 %0, %4, off nt\n\t"                     \
                 "global_load_dwordx4 %1, %4, off offset:1024 nt\n\t"         \
                 "global_load_dwordx4 %2, %4, off offset:2048 nt\n\t"         \
                 "global_load_dwordx4 %3, %4, off offset:3072 nt"             \
                 : "=&v"(d0), "=&v"(d1), "=&v"(d2), "=&v"(d3)                 \
                 : "v"(p))

#define ACCUM(o, t, n)                                                        \
    dto += o.x*t.x + o.y*t.y + o.z*t.z + o.w*t.w;                             \
    dno += o.x*n.x + o.y*n.y + o.z*n.z + o.w*n.w;                             \
    oo  += o.x*o.x + o.y*o.y + o.z*o.z + o.w*o.w;                             \
    tt  += t.x*t.x + t.y*t.y + t.z*t.z + t.w*t.w;                             \
    nn  += n.x*n.x + n.y*n.y + n.z*n.z + n.w*n.w

__device__ __forceinline__ float finish(float dto, float dno, float oo,
                                        float tt, float nn) {
    dto = dpp_wave_sum(dto);
    dno = dpp_wave_sum(dno);
    oo  = dpp_wave_sum(oo);
    tt  = dpp_wave_sum(tt);
    nn  = dpp_wave_sum(nn);
    float no = sqrtf(oo);
    float h  = 1.f - dto / fmaxf(sqrtf(tt) * no, EPS)
                   + dno / fmaxf(sqrtf(nn) * no, EPS);
    return fmaxf(h, 0.f);        // valid in lane 63
}

__global__ __launch_bounds__(256, 4) void hinge_cos_kernel(
    const float* __restrict__ outm,   // [B, D]
    const float* __restrict__ tgt,    // [B, D]
    const int*   __restrict__ negidx, // [B]
    float* __restrict__ res,          // [1] scalar (pre-zeroed)
    int B, int D, float invB) {

    const int lane  = threadIdx.x & 63;
    const int wave  = threadIdx.x >> 6;
    const int wpb   = blockDim.x >> 6;           // 4
    const int gwave = blockIdx.x * wpb + wave;
    const int nwav  = gridDim.x * wpb;           // 8192

    const int i0 = gwave;
    const int i1 = i0 + nwav;

    float acc = 0.f;                             // lane-63 hinge sum

    if (i0 < B && i1 < B) {
        // Gather indices first; their waits resolve before any asm issues.
        int g0 = negidx[i0];
        int g1 = negidx[i1];
        int j0 = i0 + 1 + g0; if (j0 >= B) j0 -= B;
        int j1 = i1 + 1 + g1; if (j1 >= B) j1 -= B;

        const float* pao = outm + (size_t)i0 * D + lane * 4;
        const float* pat = tgt  + (size_t)i0 * D + lane * 4;
        const float* pan = tgt  + (size_t)j0 * D + lane * 4;
        const float* pbo = outm + (size_t)i1 * D + lane * 4;
        const float* pbt = tgt  + (size_t)i1 * D + lane * 4;
        const float* pbn = tgt  + (size_t)j1 * D + lane * 4;

        f4 ao0, ao1, ao2, ao3, at0, at1, at2, at3, an0, an1, an2, an3;
        f4 bo0, bo1, bo2, bo3, bt0, bt1, bt2, bt3, bn0, bn1, bn2, bn3;

        LOAD4_NT(ao0, ao1, ao2, ao3, pao);       // row A: 12 loads
        LOAD4   (at0, at1, at2, at3, pat);
        LOAD4   (an0, an1, an2, an3, pan);
        LOAD4_NT(bo0, bo1, bo2, bo3, pbo);       // row B: 12 loads
        LOAD4   (bt0, bt1, bt2, bt3, pbt);
        LOAD4   (bn0, bn1, bn2, bn3, pbn);
        // 24 KB/wave in flight.

        asm volatile("s_waitcnt vmcnt(12)");     // row A complete; B in flight
        __builtin_amdgcn_sched_barrier(0);
        {
            float dto = 0.f, dno = 0.f, oo = 0.f, tt = 0.f, nn = 0.f;
            ACCUM(ao0, at0, an0); ACCUM(ao1, at1, an1);
            ACCUM(ao2, at2, an2); ACCUM(ao3, at3, an3);
            float h = finish(dto, dno, oo, tt, nn);
            if (lane == 63) acc += h;
        }
        asm volatile("s_waitcnt vmcnt(0)");      // row B complete
        __builtin_amdgcn_sched_barrier(0);
        {
            float dto = 0.f, dno = 0.f, oo = 0.f, tt = 0.f, nn = 0.f;
            ACCUM(bo0, bt0, bn0); ACCUM(bo1, bt1, bn1);
            ACCUM(bo2, bt2, bn2); ACCUM(bo3, bt3, bn3);
            float h = finish(dto, dno, oo, tt, nn);
            if (lane == 63) acc += h;
        }
    } else if (i0 < B) {
        // Generic tail (not hit at B=16384): plain compiler-managed path.
        int g0 = negidx[i0];
        int j0 = i0 + 1 + g0; if (j0 >= B) j0 -= B;
        const f4* o4 = (const f4*)(outm + (size_t)i0 * D);
        const f4* t4 = (const f4*)(tgt  + (size_t)i0 * D);
        const f4* n4 = (const f4*)(tgt  + (size_t)j0 * D);
        float dto = 0.f, dno = 0.f, oo = 0.f, tt = 0.f, nn = 0.f;
#pragma unroll
        for (int k = 0; k < 4; ++k) {
            f4 o = o4[lane + 64 * k], t = t4[lane + 64 * k], n = n4[lane + 64 * k];
            ACCUM(o, t, n);
        }
        float h = finish(dto, dno, oo, tt, nn);
        if (lane == 63) acc += h;
    }

    // Block-level: lane 63 of each wave holds its partial; one atomic per block.
    __shared__ float red[4];
    if (lane == 63) red[wave] = acc;
    __syncthreads();
    if (threadIdx.x == 0) {
        float s = red[0] + red[1] + red[2] + red[3];
        atomicAdd(res, s * invB);
    }
}

extern "C" void kernel_launch(void* const* d_in, const int* in_sizes, int n_in,
                              void* d_out, int out_size, void* d_ws, size_t ws_size,
                              hipStream_t stream) {
    const float* outm   = (const float*)d_in[0];
    const float* tgt    = (const float*)d_in[1];
    const int*   negidx = (const int*)d_in[2];
    float* res = (float*)d_out;

    const int B = in_sizes[2];
    const int D = in_sizes[0] / B;

    (void)hipMemsetAsync(res, 0, sizeof(float), stream);

    // Two rows per wave: nwav = ceil(B/2), 4 waves per 256-thread block.
    const int nwav   = (B + 1) / 2;               // 8192
    const int blocks = (nwav + 3) / 4;            // 2048
    hinge_cos_kernel<<<blocks, 256, 0, stream>>>(outm, tgt, negidx, res, B, D,
                                                 1.0f / (float)B);
}

// Round 6
// 148.411 us; speedup vs baseline: 1.1617x; 1.0063x over previous
//
#include <hip/hip_runtime.h>
#include <stdint.h>

// Row-wise cosine hinge loss.
//   j = (i + 1 + neg_idx[i]) % B
//   hinge_i = relu(1 - cos(t_i, o_i) + cos(t_j, o_i))
//   out = sum_i hinge_i / B
//
// R6 = R5 with the compile fix: row bases forced into SGPRs via
// readfirstlane (they ARE wave-uniform; the compiler just can't prove it
// from threadIdx-derived math, so the "s" constraint got VGPR pairs ->
// invalid saddr operand). Design per R4 post-mortem:
//  - SGPR base pairs + ONE shared VGPR offset (lane*16): address pressure
//    ~1 VGPR instead of ~24, removing the allocator's AGPR-parking motive
//  - 2 rolling row-buffers across 4 rows: peak ~110 data VGPRs
//  - launch_bounds(256,2): 256-reg budget, zero spill pressure; ~110 alloc
//    still yields 4 waves/EU (16/CU, same occupancy as the 40.7us R1)
//  - rolling counted waits: issue r0,r1 | vmcnt(12) consume r0, issue r2 |
//    vmcnt(12) consume r1, issue r3 | vmcnt(12) consume r2 | vmcnt(0)
//    consume r3. sched_barrier(0) after each wait (guide rule 18).

#define EPS 1e-6f

typedef float f4 __attribute__((ext_vector_type(4)));

// VALU-pipe wave reduction via DPP; lane 63 holds the 64-lane sum.
#define DPP_STEP(x, ctrl, rm, bm)                                             \
    x += __int_as_float(__builtin_amdgcn_update_dpp(                          \
        0, __float_as_int(x), (ctrl), (rm), (bm), true))

__device__ __forceinline__ float dpp_wave_sum(float x) {
    DPP_STEP(x, 0x111, 0xf, 0xf);  // row_shr:1
    DPP_STEP(x, 0x112, 0xf, 0xf);  // row_shr:2
    DPP_STEP(x, 0x114, 0xf, 0xe);  // row_shr:4
    DPP_STEP(x, 0x118, 0xf, 0xc);  // row_shr:8
    DPP_STEP(x, 0x142, 0xa, 0xf);  // row_bcast:15
    DPP_STEP(x, 0x143, 0xc, 0xf);  // row_bcast:31
    return x;                      // valid in lane 63
}

// Force a wave-uniform 64-bit value into an SGPR pair.
__device__ __forceinline__ uint64_t to_sgpr(const void* p) {
    uint64_t x = (uint64_t)p;
    uint32_t lo = __builtin_amdgcn_readfirstlane((uint32_t)x);
    uint32_t hi = __builtin_amdgcn_readfirstlane((uint32_t)(x >> 32));
    return ((uint64_t)hi << 32) | lo;
}

// 4x global_load_dwordx4 covering one 4KB row: SGPR base pair + shared
// VGPR lane offset (lane*16). 13-bit signed imm covers +3072.
#define LOAD4S(d0, d1, d2, d3, voff, base)                                    \
    asm volatile("global_load_dwordx4 %0, %4, %5\n\t"                         \
                 "global_load_dwordx4 %1, %4, %5 offset:1024\n\t"             \
                 "global_load_dwordx4 %2, %4, %5 offset:2048\n\t"             \
                 "global_load_dwordx4 %3, %4, %5 offset:3072"                 \
                 : "=&v"(d0), "=&v"(d1), "=&v"(d2), "=&v"(d3)                 \
                 : "v"(voff), "s"(base))

#define ISSUE_ROW(P, ob, tb, nb)                                              \
    LOAD4S(P##o0, P##o1, P##o2, P##o3, voff, ob);                             \
    LOAD4S(P##t0, P##t1, P##t2, P##t3, voff, tb);                             \
    LOAD4S(P##n0, P##n1, P##n2, P##n3, voff, nb)

#define ACC1(o, t, n)                                                         \
    dto += o.x*t.x + o.y*t.y + o.z*t.z + o.w*t.w;                             \
    dno += o.x*n.x + o.y*n.y + o.z*n.z + o.w*n.w;                             \
    oo  += o.x*o.x + o.y*o.y + o.z*o.z + o.w*o.w;                             \
    tt  += t.x*t.x + t.y*t.y + t.z*t.z + t.w*t.w;                             \
    nn  += n.x*n.x + n.y*n.y + n.z*n.z + n.w*n.w

// Consume one row-buffer (P in {A,B}); adds hinge to acc on lane 63.
#define CONSUME_ROW(P)                                                        \
    do {                                                                      \
        float dto = 0.f, dno = 0.f, oo = 0.f, tt = 0.f, nn = 0.f;             \
        ACC1(P##o0, P##t0, P##n0); ACC1(P##o1, P##t1, P##n1);                 \
        ACC1(P##o2, P##t2, P##n2); ACC1(P##o3, P##t3, P##n3);                 \
        dto = dpp_wave_sum(dto);                                              \
        dno = dpp_wave_sum(dno);                                              \
        oo  = dpp_wave_sum(oo);                                               \
        tt  = dpp_wave_sum(tt);                                               \
        nn  = dpp_wave_sum(nn);                                               \
        float no = sqrtf(oo);                                                 \
        float h  = 1.f - dto / fmaxf(sqrtf(tt) * no, EPS)                     \
                       + dno / fmaxf(sqrtf(nn) * no, EPS);                    \
        if (lane == 63) acc += fmaxf(h, 0.f);                                 \
    } while (0)

#define WAIT(N)                                                               \
    asm volatile("s_waitcnt vmcnt(" #N ")");                                  \
    __builtin_amdgcn_sched_barrier(0)

__global__ __launch_bounds__(256, 2) void hinge_cos_kernel(
    const float* __restrict__ outm,   // [B, D]
    const float* __restrict__ tgt,    // [B, D]
    const int*   __restrict__ negidx, // [B]
    float* __restrict__ res,          // [1] scalar (pre-zeroed)
    int B, int D, float invB) {

    const int lane  = threadIdx.x & 63;
    const int wave  = threadIdx.x >> 6;
    const int gwave = blockIdx.x * 4 + wave;
    const int nwav  = gridDim.x * 4;             // 4096

    const int i0 = gwave;
    const int i1 = i0 + nwav;
    const int i2 = i1 + nwav;
    const int i3 = i2 + nwav;

    float acc = 0.f;                             // lane-63 hinge sum

    if (i3 < B) {
        // ALL index loads + address math upfront (wave-uniform).
        int g0 = negidx[i0], g1 = negidx[i1], g2 = negidx[i2], g3 = negidx[i3];
        int j0 = i0 + 1 + g0; if (j0 >= B) j0 -= B;
        int j1 = i1 + 1 + g1; if (j1 >= B) j1 -= B;
        int j2 = i2 + 1 + g2; if (j2 >= B) j2 -= B;
        int j3 = i3 + 1 + g3; if (j3 >= B) j3 -= B;

        const uint64_t o0b = to_sgpr(outm + (size_t)i0 * D);
        const uint64_t t0b = to_sgpr(tgt  + (size_t)i0 * D);
        const uint64_t n0b = to_sgpr(tgt  + (size_t)j0 * D);
        const uint64_t o1b = to_sgpr(outm + (size_t)i1 * D);
        const uint64_t t1b = to_sgpr(tgt  + (size_t)i1 * D);
        const uint64_t n1b = to_sgpr(tgt  + (size_t)j1 * D);
        const uint64_t o2b = to_sgpr(outm + (size_t)i2 * D);
        const uint64_t t2b = to_sgpr(tgt  + (size_t)i2 * D);
        const uint64_t n2b = to_sgpr(tgt  + (size_t)j2 * D);
        const uint64_t o3b = to_sgpr(outm + (size_t)i3 * D);
        const uint64_t t3b = to_sgpr(tgt  + (size_t)i3 * D);
        const uint64_t n3b = to_sgpr(tgt  + (size_t)j3 * D);

        const int voff = lane * 16;              // the ONE address VGPR

        f4 Ao0, Ao1, Ao2, Ao3, At0, At1, At2, At3, An0, An1, An2, An3;
        f4 Bo0, Bo1, Bo2, Bo3, Bt0, Bt1, Bt2, Bt3, Bn0, Bn1, Bn2, Bn3;

        ISSUE_ROW(A, o0b, t0b, n0b);             // r0 -> buf A (12 loads)
        ISSUE_ROW(B, o1b, t1b, n1b);             // r1 -> buf B (24 in flight)

        WAIT(12);                                // r0 done, r1 in flight
        CONSUME_ROW(A);
        ISSUE_ROW(A, o2b, t2b, n2b);             // r2 -> buf A

        WAIT(12);                                // r1 done, r2 in flight
        CONSUME_ROW(B);
        ISSUE_ROW(B, o3b, t3b, n3b);             // r3 -> buf B

        WAIT(12);                                // r2 done, r3 in flight
        CONSUME_ROW(A);

        WAIT(0);                                 // r3 done
        CONSUME_ROW(B);
    } else {
        // Generic tail (not reached at B=16384): plain compiler path.
        int idx[4] = {i0, i1, i2, i3};
        for (int r = 0; r < 4; ++r) {
            int i = idx[r];
            if (i >= B) break;
            int g = negidx[i];
            int j = i + 1 + g; if (j >= B) j -= B;
            const f4* o4 = (const f4*)(outm + (size_t)i * D);
            const f4* t4 = (const f4*)(tgt  + (size_t)i * D);
            const f4* n4 = (const f4*)(tgt  + (size_t)j * D);
            float dto = 0.f, dno = 0.f, oo = 0.f, tt = 0.f, nn = 0.f;
#pragma unroll
            for (int k = 0; k < 4; ++k) {
                f4 o = o4[lane + 64*k], t = t4[lane + 64*k], n = n4[lane + 64*k];
                ACC1(o, t, n);
            }
            dto = dpp_wave_sum(dto); dno = dpp_wave_sum(dno);
            oo = dpp_wave_sum(oo); tt = dpp_wave_sum(tt); nn = dpp_wave_sum(nn);
            float no = sqrtf(oo);
            float h = 1.f - dto / fmaxf(sqrtf(tt) * no, EPS)
                          + dno / fmaxf(sqrtf(nn) * no, EPS);
            if (lane == 63) acc += fmaxf(h, 0.f);
        }
    }

    // Block-level: lane 63 of each wave holds its partial; one atomic per block.
    __shared__ float red[4];
    if (lane == 63) red[wave] = acc;
    __syncthreads();
    if (threadIdx.x == 0) {
        float s = red[0] + red[1] + red[2] + red[3];
        atomicAdd(res, s * invB);
    }
}

extern "C" void kernel_launch(void* const* d_in, const int* in_sizes, int n_in,
                              void* d_out, int out_size, void* d_ws, size_t ws_size,
                              hipStream_t stream) {
    const float* outm   = (const float*)d_in[0];
    const float* tgt    = (const float*)d_in[1];
    const int*   negidx = (const int*)d_in[2];
    float* res = (float*)d_out;

    const int B = in_sizes[2];
    const int D = in_sizes[0] / B;

    (void)hipMemsetAsync(res, 0, sizeof(float), stream);

    // Four rows per wave: nwav = ceil(B/4) waves, 4 waves per block.
    const int nwav   = (B + 3) / 4;               // 4096
    const int blocks = (nwav + 3) / 4;            // 1024
    hinge_cos_kernel<<<blocks, 256, 0, stream>>>(outm, tgt, negidx, res, B, D,
                                                 1.0f / (float)B);
}

// Round 7
// 145.633 us; speedup vs baseline: 1.1839x; 1.0191x over previous
//
#include <hip/hip_runtime.h>
#include <stdint.h>

// Row-wise cosine hinge loss.
//   j = (i + 1 + neg_idx[i]) % B
//   hinge_i = relu(1 - cos(t_i, o_i) + cos(t_j, o_i))
//   out = sum_i hinge_i / B
//
// R7: global_load_lds deep-FIFO pipeline. R1/R3/R4/R6 all proved the
// register allocator serializes ANY VGPR-destined load pipeline (parks asm
// outputs via wait+copy; VGPR_Count stuck at 52-64 vs ~120 designed).
// global_load_lds sidesteps regalloc entirely: loads write LDS directly
// (no dest VGPRs), vmcnt counts them FIFO, counted waits control depth.
//   per wave: 4 rows x 4 quarter-sets (o,t,n x 1KB), 3 rotating LDS slots
//   steady state: 9 loads (9KB) in flight, s_waitcnt vmcnt(6) per step
//   consume: asm ds_read_b128 x3 + lgkmcnt(0) in-block (rule 18 safe)
// LDS 4 waves x 3 slots x 3KB = 36864B -> 4 blocks/CU, 16 waves/CU,
// 144KB/CU in flight. Per-lane accumulation order identical to prior
// rounds -> bitwise-same result.

#define EPS 1e-6f

typedef float f4 __attribute__((ext_vector_type(4)));

// VALU-pipe wave reduction via DPP; lane 63 holds the 64-lane sum.
#define DPP_STEP(x, ctrl, rm, bm)                                             \
    x += __int_as_float(__builtin_amdgcn_update_dpp(                          \
        0, __float_as_int(x), (ctrl), (rm), (bm), true))

__device__ __forceinline__ float dpp_wave_sum(float x) {
    DPP_STEP(x, 0x111, 0xf, 0xf);  // row_shr:1
    DPP_STEP(x, 0x112, 0xf, 0xf);  // row_shr:2
    DPP_STEP(x, 0x114, 0xf, 0xe);  // row_shr:4
    DPP_STEP(x, 0x118, 0xf, 0xc);  // row_shr:8
    DPP_STEP(x, 0x142, 0xa, 0xf);  // row_bcast:15
    DPP_STEP(x, 0x143, 0xc, 0xf);  // row_bcast:31
    return x;                      // valid in lane 63
}

// One global->LDS async 16B/lane load. LDS dest is wave-uniform base
// (HW adds lane*16). Counts 1 on vmcnt.
__device__ __forceinline__ void gload16(const float* g, char* l) {
    __builtin_amdgcn_global_load_lds(
        (__attribute__((address_space(1))) void*)g,
        (__attribute__((address_space(3))) void*)l, 16, 0, 0);
}

// 32-bit LDS byte address of a generic LDS pointer (for asm ds_read).
__device__ __forceinline__ uint32_t lds_addr(void* p) {
    return (uint32_t)(uintptr_t)(__attribute__((address_space(3))) char*)p;
}

#define WAITV(n)                                                              \
    asm volatile("s_waitcnt vmcnt(" #n ")" ::: "memory");                     \
    __builtin_amdgcn_sched_barrier(0)

// Read one quarter-set from slot; lgkmcnt(0) inside the block so outputs
// are valid at asm exit (no rule-18 hoist hazard).
#define DSR(slot)                                                             \
    asm volatile("ds_read_b128 %0, %3 offset:0\n\t"                           \
                 "ds_read_b128 %1, %3 offset:1024\n\t"                        \
                 "ds_read_b128 %2, %3 offset:2048\n\t"                        \
                 "s_waitcnt lgkmcnt(0)"                                       \
                 : "=&v"(vo), "=&v"(vt), "=&v"(vn)                            \
                 : "v"(va##slot))

// Issue quarter-set (row r, quarter q) into slot: 3 gload16 (3KB).
#define ISSUE3(slot, r, q)                                                    \
    gload16(gO##r + (q)*256 + lane4, wslot##slot);                            \
    gload16(gT##r + (q)*256 + lane4, wslot##slot + 1024);                     \
    gload16(gN##r + (q)*256 + lane4, wslot##slot + 2048)

#define ACCQ()                                                                \
    dto += vo.x*vt.x + vo.y*vt.y + vo.z*vt.z + vo.w*vt.w;                     \
    dno += vo.x*vn.x + vo.y*vn.y + vo.z*vn.z + vo.w*vn.w;                     \
    oo  += vo.x*vo.x + vo.y*vo.y + vo.z*vo.z + vo.w*vo.w;                     \
    tt  += vt.x*vt.x + vt.y*vt.y + vt.z*vt.z + vt.w*vt.w;                     \
    nn  += vn.x*vn.x + vn.y*vn.y + vn.z*vn.z + vn.w*vn.w

// Step with prefetch: wait, read slot, refill same slot with set (nr,nq).
#define STEP_I(W, slot, r, q, nslot, nr, nq)                                  \
    do {                                                                      \
        WAITV(W);                                                             \
        f4 vo, vt, vn;                                                        \
        DSR(slot);                                                            \
        ISSUE3(nslot, nr, nq);                                                \
        ACCQ();                                                               \
    } while (0)

// Drain step: no refill.
#define STEP_N(W, slot, r, q)                                                 \
    do {                                                                      \
        WAITV(W);                                                             \
        f4 vo, vt, vn;                                                        \
        DSR(slot);                                                            \
        ACCQ();                                                               \
    } while (0)

#define ROWINIT() dto = dno = oo = tt = nn = 0.f

#define FIN()                                                                 \
    do {                                                                      \
        float d1 = dpp_wave_sum(dto), d2 = dpp_wave_sum(dno);                 \
        float s1 = dpp_wave_sum(oo);                                          \
        float s2 = dpp_wave_sum(tt), s3 = dpp_wave_sum(nn);                   \
        float no_ = sqrtf(s1);                                                \
        float h = 1.f - d1 / fmaxf(sqrtf(s2) * no_, EPS)                      \
                      + d2 / fmaxf(sqrtf(s3) * no_, EPS);                     \
        if (lane == 63) acc += fmaxf(h, 0.f);                                 \
    } while (0)

__global__ __launch_bounds__(256, 4) void hinge_cos_kernel(
    const float* __restrict__ outm,   // [B, D]
    const float* __restrict__ tgt,    // [B, D]
    const int*   __restrict__ negidx, // [B]
    float* __restrict__ res,          // [1] scalar (pre-zeroed)
    int B, int D, float invB) {

    const int lane  = threadIdx.x & 63;
    const int wave  = threadIdx.x >> 6;
    const int gwave = blockIdx.x * 4 + wave;
    const int nwav  = gridDim.x * 4;             // 4096

    const int i0 = gwave;
    const int i1 = i0 + nwav;
    const int i2 = i1 + nwav;
    const int i3 = i2 + nwav;

    // 4 waves x 3 slots x (o,t,n) x 1KB = 36864 B.
    __shared__ char smem[4 * 3 * 3072];
    __shared__ float red[4];

    float acc = 0.f;                             // lane-63 hinge sum

    if (i3 < B) {
        // All gather indices + row bases upfront; nothing in the pipeline
        // depends on a fresh compiler-issued VMEM op (vmcnt stays ours).
        int g0 = negidx[i0], g1 = negidx[i1], g2 = negidx[i2], g3 = negidx[i3];
        int j0 = i0 + 1 + g0; if (j0 >= B) j0 -= B;
        int j1 = i1 + 1 + g1; if (j1 >= B) j1 -= B;
        int j2 = i2 + 1 + g2; if (j2 >= B) j2 -= B;
        int j3 = i3 + 1 + g3; if (j3 >= B) j3 -= B;

        const float* gO0 = outm + (size_t)i0 * D;
        const float* gT0 = tgt  + (size_t)i0 * D;
        const float* gN0 = tgt  + (size_t)j0 * D;
        const float* gO1 = outm + (size_t)i1 * D;
        const float* gT1 = tgt  + (size_t)i1 * D;
        const float* gN1 = tgt  + (size_t)j1 * D;
        const float* gO2 = outm + (size_t)i2 * D;
        const float* gT2 = tgt  + (size_t)i2 * D;
        const float* gN2 = tgt  + (size_t)j2 * D;
        const float* gO3 = outm + (size_t)i3 * D;
        const float* gT3 = tgt  + (size_t)i3 * D;
        const float* gN3 = tgt  + (size_t)j3 * D;

        const int lane4 = lane * 4;              // float offset (16B/lane)

        char* wb     = &smem[wave * 9216];
        char* wslot0 = wb;
        char* wslot1 = wb + 3072;
        char* wslot2 = wb + 6144;
        const uint32_t vabase = lds_addr(wb) + (uint32_t)(lane * 16);
        const uint32_t va0 = vabase;
        const uint32_t va1 = vabase + 3072;
        const uint32_t va2 = vabase + 6144;

        float dto, dno, oo, tt, nn;

        // Prologue: sets 0,1,2 (r0q0, r0q1, r0q2) -> 9 loads in flight.
        ISSUE3(0, 0, 0);
        ISSUE3(1, 0, 1);
        ISSUE3(2, 0, 2);

        // 16 steps; set n -> slot n%3; wait leaves 2 sets (6 loads) in
        // flight until the drain tail.
        ROWINIT();
        STEP_I(6, 0, 0, 0, 0, 0, 3);
        STEP_I(6, 1, 0, 1, 1, 1, 0);
        STEP_I(6, 2, 0, 2, 2, 1, 1);
        STEP_I(6, 0, 0, 3, 0, 1, 2);
        FIN();
        ROWINIT();
        STEP_I(6, 1, 1, 0, 1, 1, 3);
        STEP_I(6, 2, 1, 1, 2, 2, 0);
        STEP_I(6, 0, 1, 2, 0, 2, 1);
        STEP_I(6, 1, 1, 3, 1, 2, 2);
        FIN();
        ROWINIT();
        STEP_I(6, 2, 2, 0, 2, 2, 3);
        STEP_I(6, 0, 2, 1, 0, 3, 0);
        STEP_I(6, 1, 2, 2, 1, 3, 1);
        STEP_I(6, 2, 2, 3, 2, 3, 2);
        FIN();
        ROWINIT();
        STEP_I(6, 0, 3, 0, 0, 3, 3);
        STEP_N(6, 1, 3, 1);
        STEP_N(3, 2, 3, 2);
        STEP_N(0, 0, 3, 3);
        FIN();
    } else {
        // Generic tail (not reached at B=16384): plain compiler path.
        int idx[4] = {i0, i1, i2, i3};
        for (int r = 0; r < 4; ++r) {
            int i = idx[r];
            if (i >= B) break;
            int g = negidx[i];
            int j = i + 1 + g; if (j >= B) j -= B;
            const f4* o4 = (const f4*)(outm + (size_t)i * D);
            const f4* t4 = (const f4*)(tgt  + (size_t)i * D);
            const f4* n4 = (const f4*)(tgt  + (size_t)j * D);
            float dto = 0.f, dno = 0.f, oo = 0.f, tt = 0.f, nn = 0.f;
#pragma unroll
            for (int k = 0; k < 4; ++k) {
                f4 vo = o4[lane + 64*k], vt = t4[lane + 64*k], vn = n4[lane + 64*k];
                ACCQ();
            }
            float acc_local;
            (void)acc_local;
            FIN();
        }
    }

    // Block-level: lane 63 of each wave holds its partial; one atomic per block.
    if (lane == 63) red[wave] = acc;
    __syncthreads();
    if (threadIdx.x == 0) {
        float s = red[0] + red[1] + red[2] + red[3];
        atomicAdd(res, s * invB);
    }
}

extern "C" void kernel_launch(void* const* d_in, const int* in_sizes, int n_in,
                              void* d_out, int out_size, void* d_ws, size_t ws_size,
                              hipStream_t stream) {
    const float* outm   = (const float*)d_in[0];
    const float* tgt    = (const float*)d_in[1];
    const int*   negidx = (const int*)d_in[2];
    float* res = (float*)d_out;

    const int B = in_sizes[2];
    const int D = in_sizes[0] / B;

    (void)hipMemsetAsync(res, 0, sizeof(float), stream);

    // Four rows per wave: nwav = ceil(B/4) waves, 4 waves per block.
    const int nwav   = (B + 3) / 4;               // 4096
    const int blocks = (nwav + 3) / 4;            // 1024
    hinge_cos_kernel<<<blocks, 256, 0, stream>>>(outm, tgt, negidx, res, B, D,
                                                 1.0f / (float)B);
}

// Round 8
// 142.410 us; speedup vs baseline: 1.2107x; 1.0226x over previous
//
#include <hip/hip_runtime.h>

// Row-wise cosine hinge loss.
//   j = (i + 1 + neg_idx[i]) % B
//   hinge_i = relu(1 - cos(t_i, o_i) + cos(t_j, o_i))
//   out = sum_i hinge_i / B
//
// FINAL (revert to the measured-best R1 structure, kernel 40.7us):
// wave-per-row, static 4-row depth-2 A/B register pipeline, indices
// hoisted, compiler-scheduled loads. Rounds 2-7 established this sits at
// the memory-system ceiling for its access pattern:
//   - R2: 32 waves/CU via launch_bounds(256,8) -> VGPR-32 convoy, 67us
//   - R3: 32 waves/CU, 2 rows/wave -> 43us
//   - R4/R6: inline-asm VGPR pipelines -> regalloc re-serialized, 42-47us
//   - R7: global_load_lds 9-deep FIFO (regalloc-immune, guaranteed
//     outstanding) -> 46us, NULL vs convoy
// Invariant across all: FETCH ~96 MB, ~201 MB lane-delivered, 40.7-47us
// => ~4.9 TB/s delivered ceiling (78% of m13 streaming copy) for
// 2 linear streams + random-4KB-row gather, ~50% L3-served. CU-side
// structure does not move it; the residual vs pure copy is the gather's
// channel imbalance.

#define EPS 1e-6f

typedef float f4 __attribute__((ext_vector_type(4)));

// VALU-pipe wave reduction via DPP; lane 63 holds the 64-lane sum.
#define DPP_STEP(x, ctrl, rm, bm)                                             \
    x += __int_as_float(__builtin_amdgcn_update_dpp(                          \
        0, __float_as_int(x), (ctrl), (rm), (bm), true))

__device__ __forceinline__ float dpp_wave_sum(float x) {
    DPP_STEP(x, 0x111, 0xf, 0xf);  // row_shr:1
    DPP_STEP(x, 0x112, 0xf, 0xf);  // row_shr:2
    DPP_STEP(x, 0x114, 0xf, 0xe);  // row_shr:4
    DPP_STEP(x, 0x118, 0xf, 0xc);  // row_shr:8
    DPP_STEP(x, 0x142, 0xa, 0xf);  // row_bcast:15
    DPP_STEP(x, 0x143, 0xc, 0xf);  // row_bcast:31
    return x;                      // valid in lane 63
}

struct RowBuf {
    f4 o[4], t[4], n[4];
};

__device__ __forceinline__ void issue_loads(RowBuf& rb,
                                            const float* __restrict__ outm,
                                            const float* __restrict__ tgt,
                                            int i, int j, int lane, int D) {
    const f4* o4 = (const f4*)(outm + (size_t)i * D);
    const f4* t4 = (const f4*)(tgt  + (size_t)i * D);
    const f4* n4 = (const f4*)(tgt  + (size_t)j * D);
#pragma unroll
    for (int k = 0; k < 4; ++k)
        rb.o[k] = __builtin_nontemporal_load(&o4[lane + 64 * k]);  // single-use stream
#pragma unroll
    for (int k = 0; k < 4; ++k) rb.t[k] = t4[lane + 64 * k];       // keep in L3 for gathers
#pragma unroll
    for (int k = 0; k < 4; ++k) rb.n[k] = n4[lane + 64 * k];
}

// Returns this row's hinge value (valid in lane 63; other lanes garbage).
__device__ __forceinline__ float consume(const RowBuf& rb) {
    float dto = 0.f, dno = 0.f, oo = 0.f, tt = 0.f, nn = 0.f;
#pragma unroll
    for (int k = 0; k < 4; ++k) {
        dto += rb.o[k].x*rb.t[k].x + rb.o[k].y*rb.t[k].y + rb.o[k].z*rb.t[k].z + rb.o[k].w*rb.t[k].w;
        dno += rb.o[k].x*rb.n[k].x + rb.o[k].y*rb.n[k].y + rb.o[k].z*rb.n[k].z + rb.o[k].w*rb.n[k].w;
        oo  += rb.o[k].x*rb.o[k].x + rb.o[k].y*rb.o[k].y + rb.o[k].z*rb.o[k].z + rb.o[k].w*rb.o[k].w;
        tt  += rb.t[k].x*rb.t[k].x + rb.t[k].y*rb.t[k].y + rb.t[k].z*rb.t[k].z + rb.t[k].w*rb.t[k].w;
        nn  += rb.n[k].x*rb.n[k].x + rb.n[k].y*rb.n[k].y + rb.n[k].z*rb.n[k].z + rb.n[k].w*rb.n[k].w;
    }
    dto = dpp_wave_sum(dto);
    dno = dpp_wave_sum(dno);
    oo  = dpp_wave_sum(oo);
    tt  = dpp_wave_sum(tt);
    nn  = dpp_wave_sum(nn);
    float no = sqrtf(oo);
    float h  = 1.f - dto / fmaxf(sqrtf(tt) * no, EPS)
                   + dno / fmaxf(sqrtf(nn) * no, EPS);
    return fmaxf(h, 0.f);
}

__global__ __launch_bounds__(256, 4) void hinge_cos_kernel(
    const float* __restrict__ outm,   // [B, D]
    const float* __restrict__ tgt,    // [B, D]
    const int*   __restrict__ negidx, // [B]
    float* __restrict__ res,          // [1] scalar (pre-zeroed)
    int B, int D, float invB) {

    const int lane  = threadIdx.x & 63;
    const int wave  = threadIdx.x >> 6;
    const int wpb   = blockDim.x >> 6;           // 4
    const int gwave = blockIdx.x * wpb + wave;
    const int nwav  = gridDim.x * wpb;

    // Static 4-row assignment: this wave owns rows gwave + k*nwav, k=0..3.
    const int i0 = gwave;
    const int i1 = i0 + nwav;
    const int i2 = i1 + nwav;
    const int i3 = i2 + nwav;
    const bool v0 = i0 < B, v1 = i1 < B, v2 = i2 < B, v3 = i3 < B;

    // Hoist ALL gather indices: 4 independent loads, one wait, zero
    // dependent loads on the per-row issue path.
    int g0 = v0 ? negidx[i0] : 0;
    int g1 = v1 ? negidx[i1] : 0;
    int g2 = v2 ? negidx[i2] : 0;
    int g3 = v3 ? negidx[i3] : 0;
    int j0 = i0 + 1 + g0; if (j0 >= B) j0 -= B;
    int j1 = i1 + 1 + g1; if (j1 >= B) j1 -= B;
    int j2 = i2 + 1 + g2; if (j2 >= B) j2 -= B;
    int j3 = i3 + 1 + g3; if (j3 >= B) j3 -= B;

    float acc = 0.f;                              // per-wave hinge sum (lane 63)
    RowBuf bufA, bufB;                            // named: never runtime-indexed

    if (v0) issue_loads(bufA, outm, tgt, i0, j0, lane, D);
    if (v1) issue_loads(bufB, outm, tgt, i1, j1, lane, D);
    if (v0) { float h = consume(bufA); if (lane == 63) acc += h; }
    if (v2) issue_loads(bufA, outm, tgt, i2, j2, lane, D);
    if (v1) { float h = consume(bufB); if (lane == 63) acc += h; }
    if (v3) issue_loads(bufB, outm, tgt, i3, j3, lane, D);
    if (v2) { float h = consume(bufA); if (lane == 63) acc += h; }
    if (v3) { float h = consume(bufB); if (lane == 63) acc += h; }

    // Block-level: lane 63 of each wave holds its partial; one atomic per block.
    __shared__ float red[4];
    if (lane == 63) red[wave] = acc;
    __syncthreads();
    if (threadIdx.x == 0) {
        float s = 0.f;
#pragma unroll
        for (int w = 0; w < 4; ++w) s += red[w];
        atomicAdd(res, s * invB);
    }
}

extern "C" void kernel_launch(void* const* d_in, const int* in_sizes, int n_in,
                              void* d_out, int out_size, void* d_ws, size_t ws_size,
                              hipStream_t stream) {
    const float* outm   = (const float*)d_in[0];
    const float* tgt    = (const float*)d_in[1];
    const int*   negidx = (const int*)d_in[2];
    float* res = (float*)d_out;

    const int B = in_sizes[2];
    const int D = in_sizes[0] / B;

    (void)hipMemsetAsync(res, 0, sizeof(float), stream);

    // Exactly 4 rows per wave: nwav = ceil(B/4), 4 waves per 256-thr block.
    const int nwav   = (B + 3) / 4;
    const int blocks = (nwav + 3) / 4;
    hinge_cos_kernel<<<blocks, 256, 0, stream>>>(outm, tgt, negidx, res, B, D,
                                                 1.0f / (float)B);
}